// Round 7
// baseline (375.900 us; speedup 1.0000x reference)
//
#include <hip/hip_runtime.h>
#include <hip/hip_bf16.h>

#define NHEADS 4
#define DIM 128
#define NEG_SLOPE 0.2f
#define POOL_CHUNK 256

typedef __bf16 bf16x8 __attribute__((ext_vector_type(8)));
typedef float  f32x4  __attribute__((ext_vector_type(4)));

__device__ __forceinline__ float lrelu(float x) { return x > 0.f ? x : NEG_SLOPE * x; }
__device__ __forceinline__ float4 lrelu4(float4 a, float4 b) {
    return make_float4(lrelu(a.x + b.x), lrelu(a.y + b.y), lrelu(a.z + b.z), lrelu(a.w + b.w));
}
__device__ __forceinline__ float4 redmax4(float4 v) {
#pragma unroll
    for (int off = 32; off >= 1; off >>= 1) {
        v.x = fmaxf(v.x, __shfl_xor(v.x, off));
        v.y = fmaxf(v.y, __shfl_xor(v.y, off));
        v.z = fmaxf(v.z, __shfl_xor(v.z, off));
        v.w = fmaxf(v.w, __shfl_xor(v.w, off));
    }
    return v;
}
__device__ __forceinline__ float4 redsum4(float4 v) {
#pragma unroll
    for (int off = 32; off >= 1; off >>= 1) {
        v.x += __shfl_xor(v.x, off);
        v.y += __shfl_xor(v.y, off);
        v.z += __shfl_xor(v.z, off);
        v.w += __shfl_xor(v.w, off);
    }
    return v;
}

// ---------------- W pre-pack: fp32 [3][128][128] -> bf16 MFMA B-fragments ----------
__global__ __launch_bounds__(256) void pack_w(
    const float* __restrict__ Ws, __bf16* __restrict__ Wb, int total)
{
    int o = blockIdx.x * 256 + threadIdx.x;
    if (o >= total) return;
    int layer = o >> 14;
    int t = o & 16383;
    int j = t & 7, l = (t >> 3) & 63, kk = (t >> 9) & 3, g = t >> 11;
    int col = g * 16 + (l & 15);
    int k = kk * 32 + (l >> 4) * 8 + j;
    Wb[o] = (__bf16)Ws[(size_t)layer * 16384 + col * 128 + k];
}

// ---------------- bf16-MFMA GEMM + fused attention coefficients ----------------
template<bool RELU_IN>
__global__ __launch_bounds__(256) void gemm_mfma(
    const float* __restrict__ in, const uint4* __restrict__ Wb4,
    const float* __restrict__ bias,
    const float* __restrict__ attl, const float* __restrict__ attr,
    __bf16* __restrict__ xlb, float* __restrict__ al, float* __restrict__ ar, int n)
{
    const int tid = threadIdx.x;
    const int wid = tid >> 6, l = tid & 63;
    const int rowA = blockIdx.x * 64 + wid * 16 + (l & 15);
    const int kchunk = (l >> 4) * 8;

    f32x4 acc[8];
#pragma unroll
    for (int g = 0; g < 8; ++g)
#pragma unroll
        for (int r = 0; r < 4; ++r) acc[g][r] = 0.f;

#pragma unroll
    for (int kk = 0; kk < 4; ++kk) {
        float av[8];
        if (rowA < n) {
            const float* p = in + (size_t)rowA * DIM + kk * 32 + kchunk;
            float4 x0 = *(const float4*)p;
            float4 x1 = *(const float4*)(p + 4);
            av[0]=x0.x; av[1]=x0.y; av[2]=x0.z; av[3]=x0.w;
            av[4]=x1.x; av[5]=x1.y; av[6]=x1.z; av[7]=x1.w;
            if (RELU_IN) {
#pragma unroll
                for (int i = 0; i < 8; ++i) av[i] = fmaxf(av[i], 0.f);
            }
        } else {
#pragma unroll
            for (int i = 0; i < 8; ++i) av[i] = 0.f;
        }
        bf16x8 afrag;
#pragma unroll
        for (int i = 0; i < 8; ++i) afrag[i] = (__bf16)av[i];
#pragma unroll
        for (int g = 0; g < 8; ++g) {
            uint4 u = Wb4[(g * 4 + kk) * 64 + l];
            bf16x8 bfrag = __builtin_bit_cast(bf16x8, u);
            acc[g] = __builtin_amdgcn_mfma_f32_16x16x32_bf16(afrag, bfrag, acc[g], 0, 0, 0);
        }
    }

    const int rowbase = blockIdx.x * 64 + wid * 16 + (l >> 4) * 4;
    float pl[4][4], pr2[4][4];
#pragma unroll
    for (int r = 0; r < 4; ++r)
#pragma unroll
        for (int h = 0; h < 4; ++h) { pl[r][h] = 0.f; pr2[r][h] = 0.f; }

#pragma unroll
    for (int g = 0; g < 8; ++g) {
        int col = g * 16 + (l & 15);
        float bg = bias[col], alg = attl[col], arg = attr[col];
        int h = g >> 1;
#pragma unroll
        for (int r = 0; r < 4; ++r) {
            float v = acc[g][r] + bg;
            int row = rowbase + r;
            if (row < n) xlb[(size_t)row * DIM + col] = (__bf16)v;
            pl[r][h]  = fmaf(v, alg, pl[r][h]);
            pr2[r][h] = fmaf(v, arg, pr2[r][h]);
        }
    }
#pragma unroll
    for (int off = 1; off <= 8; off <<= 1) {
#pragma unroll
        for (int r = 0; r < 4; ++r)
#pragma unroll
            for (int h = 0; h < 4; ++h) {
                pl[r][h]  += __shfl_xor(pl[r][h], off);
                pr2[r][h] += __shfl_xor(pr2[r][h], off);
            }
    }
    if ((l & 15) == 0) {
#pragma unroll
        for (int r = 0; r < 4; ++r) {
            int row = rowbase + r;
            if (row < n) {
#pragma unroll
                for (int h = 0; h < 4; ++h) {
                    al[row * 4 + h] = pl[r][h];
                    ar[row * 4 + h] = pr2[r][h];
                }
            }
        }
    }
}

// ---------------- CSR build ----------------
__global__ __launch_bounds__(256) void deg_count(
    const int* __restrict__ dst, int* __restrict__ deg, int E)
{
    int e = blockIdx.x * blockDim.x + threadIdx.x;
    if (e < E) atomicAdd(&deg[dst[e]], 1);
}

__global__ __launch_bounds__(256) void scan_blocks(
    const int* __restrict__ deg, int* __restrict__ rowptr,
    int* __restrict__ partials, int n)
{
    __shared__ int tot[256];
    int t = threadIdx.x;
    int base = blockIdx.x * 1024 + t * 4;
    int v[4];
#pragma unroll
    for (int j = 0; j < 4; ++j) v[j] = (base + j < n) ? deg[base + j] : 0;
    int p1 = v[0], p2 = p1 + v[1], p3 = p2 + v[2], sum4 = p3 + v[3];
    tot[t] = sum4;
    __syncthreads();
    int val = sum4;
    for (int off = 1; off < 256; off <<= 1) {
        int other = (t >= off) ? tot[t - off] : 0;
        __syncthreads();
        val += other;
        tot[t] = val;
        __syncthreads();
    }
    int excl = val - sum4;
    if (base < n)     rowptr[base]     = excl;
    if (base+1 < n)   rowptr[base+1]   = excl + p1;
    if (base+2 < n)   rowptr[base+2]   = excl + p2;
    if (base+3 < n)   rowptr[base+3]   = excl + p3;
    if (t == 255) partials[blockIdx.x] = val;
}

__global__ __launch_bounds__(256) void scan_partials(
    int* __restrict__ partials, int nb, int* __restrict__ rowptr, int n)
{
    __shared__ int tot[256];
    int t = threadIdx.x;
    int v = (t < nb) ? partials[t] : 0;
    tot[t] = v;
    __syncthreads();
    int val = v;
    for (int off = 1; off < 256; off <<= 1) {
        int other = (t >= off) ? tot[t - off] : 0;
        __syncthreads();
        val += other;
        tot[t] = val;
        __syncthreads();
    }
    if (t < nb) partials[t] = val - v;
    if (t == 255) rowptr[n] = val;
}

__global__ __launch_bounds__(256) void add_offsets(
    int* __restrict__ rowptr, int* __restrict__ wpos,
    const int* __restrict__ partials, int n)
{
    int base = blockIdx.x * 1024 + threadIdx.x * 4;
    int off = partials[blockIdx.x];
#pragma unroll
    for (int j = 0; j < 4; ++j) {
        int i = base + j;
        if (i < n) { int r = rowptr[i] + off; rowptr[i] = r; wpos[i] = r; }
    }
}

// non-temporal store: bypass per-XCD L2 write-allocate; scattered 4B stores
// merge in the shared memory-side Infinity Cache instead of 8 private L2s.
__global__ __launch_bounds__(256) void scatter_edges(
    const int* __restrict__ src, const int* __restrict__ dst,
    int* __restrict__ wpos, int* __restrict__ col, int E)
{
    int e = blockIdx.x * blockDim.x + threadIdx.x;
    if (e >= E) return;
    int p = atomicAdd(&wpos[dst[e]], 1);
    __builtin_nontemporal_store(src[e], &col[p]);
}

// ---- accumulate one edge: 16 lanes/edge, 8 ch per lane (uint4 = 8 bf16) ----
__device__ __forceinline__ void agg_edge(
    const unsigned short* __restrict__ xp, int s, float w, f32x4& lo, f32x4& hi)
{
    uint4 v = *(const uint4*)(xp + (size_t)s * DIM);
    lo[0] = fmaf(w, __uint_as_float(v.x << 16), lo[0]);
    lo[1] = fmaf(w, __uint_as_float(v.x & 0xffff0000u), lo[1]);
    lo[2] = fmaf(w, __uint_as_float(v.y << 16), lo[2]);
    lo[3] = fmaf(w, __uint_as_float(v.y & 0xffff0000u), lo[3]);
    hi[0] = fmaf(w, __uint_as_float(v.z << 16), hi[0]);
    hi[1] = fmaf(w, __uint_as_float(v.z & 0xffff0000u), hi[1]);
    hi[2] = fmaf(w, __uint_as_float(v.w << 16), hi[2]);
    hi[3] = fmaf(w, __uint_as_float(v.w & 0xffff0000u), hi[3]);
}

// chunk of <=64 staged edges; 4 edge-groups (g=lane>>4), 16 edges in flight.
__device__ __forceinline__ void agg_chunk4(
    const int* __restrict__ slds, const float* __restrict__ wl,
    int cn, int g, const unsigned short* __restrict__ xp,
    f32x4& A0, f32x4& A1, f32x4& B0, f32x4& B1,
    f32x4& C0, f32x4& C1, f32x4& D0, f32x4& D1)
{
    int i = 0;
    for (; i + 16 <= cn; i += 16) {
        int e0 = i + g, e1 = i + 4 + g, e2 = i + 8 + g, e3 = i + 12 + g;
        int s0 = slds[e0], s1 = slds[e1], s2 = slds[e2], s3 = slds[e3];
        float w0 = wl[e0*4], w1 = wl[e1*4], w2 = wl[e2*4], w3 = wl[e3*4];
        const uint4* p0 = (const uint4*)(xp + (size_t)s0 * DIM);
        const uint4* p1 = (const uint4*)(xp + (size_t)s1 * DIM);
        const uint4* p2 = (const uint4*)(xp + (size_t)s2 * DIM);
        const uint4* p3 = (const uint4*)(xp + (size_t)s3 * DIM);
        uint4 v0 = *p0, v1 = *p1, v2 = *p2, v3 = *p3;
        A0[0] = fmaf(w0, __uint_as_float(v0.x << 16), A0[0]);
        A0[1] = fmaf(w0, __uint_as_float(v0.x & 0xffff0000u), A0[1]);
        A0[2] = fmaf(w0, __uint_as_float(v0.y << 16), A0[2]);
        A0[3] = fmaf(w0, __uint_as_float(v0.y & 0xffff0000u), A0[3]);
        A1[0] = fmaf(w0, __uint_as_float(v0.z << 16), A1[0]);
        A1[1] = fmaf(w0, __uint_as_float(v0.z & 0xffff0000u), A1[1]);
        A1[2] = fmaf(w0, __uint_as_float(v0.w << 16), A1[2]);
        A1[3] = fmaf(w0, __uint_as_float(v0.w & 0xffff0000u), A1[3]);
        B0[0] = fmaf(w1, __uint_as_float(v1.x << 16), B0[0]);
        B0[1] = fmaf(w1, __uint_as_float(v1.x & 0xffff0000u), B0[1]);
        B0[2] = fmaf(w1, __uint_as_float(v1.y << 16), B0[2]);
        B0[3] = fmaf(w1, __uint_as_float(v1.y & 0xffff0000u), B0[3]);
        B1[0] = fmaf(w1, __uint_as_float(v1.z << 16), B1[0]);
        B1[1] = fmaf(w1, __uint_as_float(v1.z & 0xffff0000u), B1[1]);
        B1[2] = fmaf(w1, __uint_as_float(v1.w << 16), B1[2]);
        B1[3] = fmaf(w1, __uint_as_float(v1.w & 0xffff0000u), B1[3]);
        C0[0] = fmaf(w2, __uint_as_float(v2.x << 16), C0[0]);
        C0[1] = fmaf(w2, __uint_as_float(v2.x & 0xffff0000u), C0[1]);
        C0[2] = fmaf(w2, __uint_as_float(v2.y << 16), C0[2]);
        C0[3] = fmaf(w2, __uint_as_float(v2.y & 0xffff0000u), C0[3]);
        C1[0] = fmaf(w2, __uint_as_float(v2.z << 16), C1[0]);
        C1[1] = fmaf(w2, __uint_as_float(v2.z & 0xffff0000u), C1[1]);
        C1[2] = fmaf(w2, __uint_as_float(v2.w << 16), C1[2]);
        C1[3] = fmaf(w2, __uint_as_float(v2.w & 0xffff0000u), C1[3]);
        D0[0] = fmaf(w3, __uint_as_float(v3.x << 16), D0[0]);
        D0[1] = fmaf(w3, __uint_as_float(v3.x & 0xffff0000u), D0[1]);
        D0[2] = fmaf(w3, __uint_as_float(v3.y << 16), D0[2]);
        D0[3] = fmaf(w3, __uint_as_float(v3.y & 0xffff0000u), D0[3]);
        D1[0] = fmaf(w3, __uint_as_float(v3.z << 16), D1[0]);
        D1[1] = fmaf(w3, __uint_as_float(v3.z & 0xffff0000u), D1[1]);
        D1[2] = fmaf(w3, __uint_as_float(v3.w << 16), D1[2]);
        D1[3] = fmaf(w3, __uint_as_float(v3.w & 0xffff0000u), D1[3]);
    }
#pragma unroll 4
    for (; i < cn; i += 4) {
        int e = i + g;
        if (e < cn) agg_edge(xp, slds[e], wl[e*4], A0, A1);
    }
}

// ---------------- fused per-node softmax + aggregate (bf16 gather) ----------
// one wave per dst node; g=lane>>4 edge group, c16=lane&15 owns ch [c16*8..+7].
__global__ __launch_bounds__(256) void gat_aggregate(
    const int* __restrict__ rowptr, const int* __restrict__ col,
    const float* __restrict__ al, const float* __restrict__ ar,
    const unsigned short* __restrict__ xlb, float* __restrict__ out, int n)
{
    __shared__ float4 wlds[4][64];
    __shared__ int    slds[4][64];
    int wid = threadIdx.x >> 6;
    int node = blockIdx.x * 4 + wid;
    if (node >= n) return;
    int lane = threadIdx.x & 63;
    int g = lane >> 4, c16 = lane & 15;
    int h = c16 >> 2;
    int r0 = rowptr[node], r1 = rowptr[node + 1];
    int deg = r1 - r0;
    float* po = out + (size_t)node * DIM + c16 * 8;
    if (deg == 0) {
        if (g == 0) {
            *(float4*)po = make_float4(0.f,0.f,0.f,0.f);
            *(float4*)(po + 4) = make_float4(0.f,0.f,0.f,0.f);
        }
        return;
    }

    float4 arv = *(const float4*)(ar + (size_t)node * 4);
    const float* wl = (const float*)&wlds[wid][0] + h;
    const unsigned short* xp = xlb + c16 * 8;
    f32x4 A0 = {0,0,0,0}, A1 = {0,0,0,0}, B0 = {0,0,0,0}, B1 = {0,0,0,0};
    f32x4 C0 = {0,0,0,0}, C1 = {0,0,0,0}, D0 = {0,0,0,0}, D1 = {0,0,0,0};
    float4 inv4;

    if (deg <= 64) {
        float4 l4 = make_float4(-1e30f, -1e30f, -1e30f, -1e30f);
        int s = 0;
        if (lane < deg) {
            s = col[r0 + lane];
            float4 a = *(const float4*)(al + (size_t)s * 4);
            l4 = lrelu4(arv, a);
        }
        float4 m4 = redmax4(l4);
        float4 p4 = make_float4(0.f, 0.f, 0.f, 0.f);
        if (lane < deg) {
            p4.x = __expf(l4.x - m4.x); p4.y = __expf(l4.y - m4.y);
            p4.z = __expf(l4.z - m4.z); p4.w = __expf(l4.w - m4.w);
        }
        float4 s4 = redsum4(p4);
        inv4 = make_float4(1.f/(s4.x+1e-16f), 1.f/(s4.y+1e-16f),
                           1.f/(s4.z+1e-16f), 1.f/(s4.w+1e-16f));
        if (lane < deg) { wlds[wid][lane] = p4; slds[wid][lane] = s; }
        __asm__ volatile("s_waitcnt lgkmcnt(0)" ::: "memory");
        __builtin_amdgcn_sched_barrier(0);
        agg_chunk4(&slds[wid][0], wl, deg, g, xp, A0, A1, B0, B1, C0, C1, D0, D1);
    } else {
        float4 m4 = make_float4(-1e30f, -1e30f, -1e30f, -1e30f);
        for (int i = lane; i < deg; i += 64) {
            int s = col[r0 + i];
            float4 a = *(const float4*)(al + (size_t)s * 4);
            float4 t = lrelu4(arv, a);
            m4.x = fmaxf(m4.x, t.x); m4.y = fmaxf(m4.y, t.y);
            m4.z = fmaxf(m4.z, t.z); m4.w = fmaxf(m4.w, t.w);
        }
        m4 = redmax4(m4);
        float4 s4 = make_float4(0.f, 0.f, 0.f, 0.f);
        for (int i = lane; i < deg; i += 64) {
            int s = col[r0 + i];
            float4 a = *(const float4*)(al + (size_t)s * 4);
            float4 t = lrelu4(arv, a);
            s4.x += __expf(t.x - m4.x); s4.y += __expf(t.y - m4.y);
            s4.z += __expf(t.z - m4.z); s4.w += __expf(t.w - m4.w);
        }
        s4 = redsum4(s4);
        inv4 = make_float4(1.f/(s4.x+1e-16f), 1.f/(s4.y+1e-16f),
                           1.f/(s4.z+1e-16f), 1.f/(s4.w+1e-16f));
        for (int c0 = 0; c0 < deg; c0 += 64) {
            int cn = min(64, deg - c0);
            if (lane < cn) {
                int s = col[r0 + c0 + lane];
                float4 a = *(const float4*)(al + (size_t)s * 4);
                float4 t = lrelu4(arv, a);
                float4 p;
                p.x = __expf(t.x - m4.x); p.y = __expf(t.y - m4.y);
                p.z = __expf(t.z - m4.z); p.w = __expf(t.w - m4.w);
                wlds[wid][lane] = p; slds[wid][lane] = s;
            }
            __asm__ volatile("s_waitcnt lgkmcnt(0)" ::: "memory");
            __builtin_amdgcn_sched_barrier(0);
            agg_chunk4(&slds[wid][0], wl, cn, g, xp, A0, A1, B0, B1, C0, C1, D0, D1);
            __asm__ volatile("s_waitcnt lgkmcnt(0)" ::: "memory");
            __builtin_amdgcn_sched_barrier(0);
        }
    }
    float invh = (h == 0) ? inv4.x : (h == 1) ? inv4.y : (h == 2) ? inv4.z : inv4.w;
    f32x4 lo, hi;
#pragma unroll
    for (int j = 0; j < 4; ++j) {
        lo[j] = A0[j] + B0[j] + C0[j] + D0[j];
        hi[j] = A1[j] + B1[j] + C1[j] + D1[j];
        lo[j] += __shfl_xor(lo[j], 16);
        lo[j] += __shfl_xor(lo[j], 32);
        hi[j] += __shfl_xor(hi[j], 16);
        hi[j] += __shfl_xor(hi[j], 32);
    }
    if (g == 0) {
        *(float4*)po       = make_float4(lo[0]*invh, lo[1]*invh, lo[2]*invh, lo[3]*invh);
        *(float4*)(po + 4) = make_float4(hi[0]*invh, hi[1]*invh, hi[2]*invh, hi[3]*invh);
    }
}

// ---------------- graph pooling: segmented (batch is sorted) ----------------
__global__ __launch_bounds__(256) void pool_nodes_seg(
    const float* __restrict__ h, const int* __restrict__ batch,
    float* __restrict__ pooled, int n)
{
    int wid = threadIdx.x >> 6;
    int lane = threadIdx.x & 63;
    int start = blockIdx.x * POOL_CHUNK;
    int end = min(start + POOL_CHUNK, n);
    float a0 = 0.f, a1 = 0.f;
    int curg = -1;
    for (int node = start + wid; node < end; node += 4) {
        int g = batch[node];
        if (g != curg) {
            if (curg >= 0) {
                unsafeAtomicAdd(pooled + (size_t)curg * DIM + lane*2,     a0);
                unsafeAtomicAdd(pooled + (size_t)curg * DIM + lane*2 + 1, a1);
            }
            curg = g; a0 = 0.f; a1 = 0.f;
        }
        float2 v = *(const float2*)(h + (size_t)node * DIM + lane * 2);
        a0 += fmaxf(v.x, 0.f);
        a1 += fmaxf(v.y, 0.f);
    }
    if (curg >= 0) {
        unsafeAtomicAdd(pooled + (size_t)curg * DIM + lane*2,     a0);
        unsafeAtomicAdd(pooled + (size_t)curg * DIM + lane*2 + 1, a1);
    }
}

// ---------------- final projection ----------------
__global__ __launch_bounds__(256) void proj_out(
    const float* __restrict__ pooled, const float* __restrict__ W,
    const float* __restrict__ b, float* __restrict__ out, int G)
{
    int idx = blockIdx.x * blockDim.x + threadIdx.x;
    if (idx >= G * 32) return;
    int g = idx >> 5, j = idx & 31;
    const float* pr = pooled + (size_t)g * DIM;
    const float* wr = W + (size_t)j * DIM;
    float acc = 0.f;
#pragma unroll
    for (int k = 0; k < DIM; ++k) acc = fmaf(pr[k], wr[k], acc);
    out[idx] = acc + b[j];
}

extern "C" void kernel_launch(void* const* d_in, const int* in_sizes, int n_in,
                              void* d_out, int out_size, void* d_ws, size_t ws_size,
                              hipStream_t stream)
{
    const float* x      = (const float*)d_in[0];
    const int*   eidx   = (const int*)d_in[1];
    const int*   batch  = (const int*)d_in[2];
    const float* Ws     = (const float*)d_in[3];
    const float* bs     = (const float*)d_in[4];
    const float* attls  = (const float*)d_in[5];
    const float* attrs  = (const float*)d_in[6];
    const float* projW  = (const float*)d_in[7];
    const float* projb  = (const float*)d_in[8];

    const int N = in_sizes[0] / DIM;
    const int E = in_sizes[1] / 2;
    const int G = out_size / 32;
    const int* src = eidx;
    const int* dst = eidx + E;

    char* ws = (char*)d_ws;
    size_t o = 0;
    auto alloc = [&](size_t bytes) { char* p = ws + o; o += (bytes + 255) & ~255ull; return p; };
    float*  hA     = (float*)alloc((size_t)N * DIM * 4);
    float*  hB     = (float*)alloc((size_t)N * DIM * 4);
    __bf16* xlb    = (__bf16*)alloc((size_t)N * DIM * 2);
    float*  al     = (float*)alloc((size_t)N * 4 * 4);
    float*  ar     = (float*)alloc((size_t)N * 4 * 4);
    int*    rowptr = (int*)alloc((size_t)(N + 1) * 4);
    int*    wpos   = (int*)alloc((size_t)N * 4);
    int*    deg    = (int*)alloc((size_t)N * 4);
    int*    colv   = (int*)alloc((size_t)E * 4);
    int*    parts  = (int*)alloc(256 * 4);
    float*  pooled = (float*)alloc((size_t)G * DIM * 4);
    __bf16* Wb     = (__bf16*)alloc((size_t)3 * 16384 * 2);

    // ---- one-time prep: W fragment pack + CSR build ----
    const int wtot = 3 * 16384;
    pack_w<<<(wtot + 255) / 256, 256, 0, stream>>>(Ws, Wb, wtot);

    const int nb = (N + 1023) / 1024;
    hipMemsetAsync(deg, 0, (size_t)N * 4, stream);
    deg_count<<<(E + 255) / 256, 256, 0, stream>>>(dst, deg, E);
    scan_blocks<<<nb, 256, 0, stream>>>(deg, rowptr, parts, N);
    scan_partials<<<1, 256, 0, stream>>>(parts, nb, rowptr, N);
    add_offsets<<<nb, 256, 0, stream>>>(rowptr, wpos, parts, N);
    scatter_edges<<<(E + 255) / 256, 256, 0, stream>>>(src, dst, wpos, colv, E);

    // ---- 3 GAT layers ----
    const float* hin = x;
    float* houts[3] = {hA, hB, hA};
    for (int l = 0; l < 3; ++l) {
        float* hout = houts[l];
        dim3 gb((N + 63) / 64);
        const uint4* Wb4 = (const uint4*)(Wb + (size_t)l * 16384);
        if (l == 0)
            gemm_mfma<false><<<gb, 256, 0, stream>>>(hin, Wb4, bs + l*DIM,
                attls + l*DIM, attrs + l*DIM, xlb, al, ar, N);
        else
            gemm_mfma<true ><<<gb, 256, 0, stream>>>(hin, Wb4, bs + l*DIM,
                attls + l*DIM, attrs + l*DIM, xlb, al, ar, N);
        gat_aggregate<<<(N + 3) / 4, 256, 0, stream>>>(rowptr, colv, al, ar,
            (const unsigned short*)xlb, hout, N);
        hin = hout;
    }

    // ---- pool + projection ----
    hipMemsetAsync(pooled, 0, (size_t)G * DIM * 4, stream);
    pool_nodes_seg<<<(N + POOL_CHUNK - 1) / POOL_CHUNK, 256, 0, stream>>>(hA, batch, pooled, N);
    proj_out<<<(G * 32 + 255) / 256, 256, 0, stream>>>(pooled, projW, projb, (float*)d_out, G);
}

// Round 8
// 319.486 us; speedup vs baseline: 1.1766x; 1.1766x over previous
//
#include <hip/hip_runtime.h>
#include <hip/hip_bf16.h>

#define NHEADS 4
#define DIM 128
#define NEG_SLOPE 0.2f
#define POOL_CHUNK 256

typedef __bf16 bf16x8 __attribute__((ext_vector_type(8)));
typedef float  f32x4  __attribute__((ext_vector_type(4)));

__device__ __forceinline__ float lrelu(float x) { return x > 0.f ? x : NEG_SLOPE * x; }
__device__ __forceinline__ float bf2f(unsigned short u) {
    return __uint_as_float(((unsigned)u) << 16);
}
__device__ __forceinline__ unsigned short f2bf(float f) {
    __bf16 b = (__bf16)f;
    return __builtin_bit_cast(unsigned short, b);
}
__device__ __forceinline__ float4 lrelu4(float4 a, float4 b) {
    return make_float4(lrelu(a.x + b.x), lrelu(a.y + b.y), lrelu(a.z + b.z), lrelu(a.w + b.w));
}
__device__ __forceinline__ float4 redmax4(float4 v) {
#pragma unroll
    for (int off = 32; off >= 1; off >>= 1) {
        v.x = fmaxf(v.x, __shfl_xor(v.x, off));
        v.y = fmaxf(v.y, __shfl_xor(v.y, off));
        v.z = fmaxf(v.z, __shfl_xor(v.z, off));
        v.w = fmaxf(v.w, __shfl_xor(v.w, off));
    }
    return v;
}
__device__ __forceinline__ float4 redsum4(float4 v) {
#pragma unroll
    for (int off = 32; off >= 1; off >>= 1) {
        v.x += __shfl_xor(v.x, off);
        v.y += __shfl_xor(v.y, off);
        v.z += __shfl_xor(v.z, off);
        v.w += __shfl_xor(v.w, off);
    }
    return v;
}

// ---------------- W pre-pack: fp32 [3][128][128] -> bf16 MFMA B-fragments ----------
__global__ __launch_bounds__(256) void pack_w(
    const float* __restrict__ Ws, __bf16* __restrict__ Wb, int total)
{
    int o = blockIdx.x * 256 + threadIdx.x;
    if (o >= total) return;
    int layer = o >> 14;
    int t = o & 16383;
    int j = t & 7, l = (t >> 3) & 63, kk = (t >> 9) & 3, g = t >> 11;
    int col = g * 16 + (l & 15);
    int k = kk * 32 + (l >> 4) * 8 + j;
    Wb[o] = (__bf16)Ws[(size_t)layer * 16384 + col * 128 + k];
}

// ---------------- bf16-MFMA GEMM body + fused attention coefficients ----------------
// A is fp32 (layer 0) or pre-relu'd bf16 (layers 1,2). No internal relu (h stored relu'd).
template<bool ABF>
__device__ __forceinline__ void gemm_body(
    const float* __restrict__ inF, const unsigned short* __restrict__ inB,
    const uint4* __restrict__ Wb4, const float* __restrict__ bias,
    const float* __restrict__ attl, const float* __restrict__ attr,
    __bf16* __restrict__ xlb, float* __restrict__ al, float* __restrict__ ar,
    int n, int bid)
{
    const int tid = threadIdx.x;
    const int wid = tid >> 6, l = tid & 63;
    const int rowA = bid * 64 + wid * 16 + (l & 15);
    const int kchunk = (l >> 4) * 8;

    f32x4 acc[8];
#pragma unroll
    for (int g = 0; g < 8; ++g)
#pragma unroll
        for (int r = 0; r < 4; ++r) acc[g][r] = 0.f;

#pragma unroll
    for (int kk = 0; kk < 4; ++kk) {
        bf16x8 afrag;
        if (ABF) {
            uint4 u = make_uint4(0, 0, 0, 0);
            if (rowA < n)
                u = *(const uint4*)(inB + (size_t)rowA * DIM + kk * 32 + kchunk);
            afrag = __builtin_bit_cast(bf16x8, u);
        } else {
            float av[8];
            if (rowA < n) {
                const float* p = inF + (size_t)rowA * DIM + kk * 32 + kchunk;
                float4 x0 = *(const float4*)p;
                float4 x1 = *(const float4*)(p + 4);
                av[0]=x0.x; av[1]=x0.y; av[2]=x0.z; av[3]=x0.w;
                av[4]=x1.x; av[5]=x1.y; av[6]=x1.z; av[7]=x1.w;
            } else {
#pragma unroll
                for (int i = 0; i < 8; ++i) av[i] = 0.f;
            }
#pragma unroll
            for (int i = 0; i < 8; ++i) afrag[i] = (__bf16)av[i];
        }
#pragma unroll
        for (int g = 0; g < 8; ++g) {
            uint4 u = Wb4[(g * 4 + kk) * 64 + l];
            bf16x8 bfrag = __builtin_bit_cast(bf16x8, u);
            acc[g] = __builtin_amdgcn_mfma_f32_16x16x32_bf16(afrag, bfrag, acc[g], 0, 0, 0);
        }
    }

    const int rowbase = bid * 64 + wid * 16 + (l >> 4) * 4;
    float pl[4][4], pr2[4][4];
#pragma unroll
    for (int r = 0; r < 4; ++r)
#pragma unroll
        for (int h = 0; h < 4; ++h) { pl[r][h] = 0.f; pr2[r][h] = 0.f; }

#pragma unroll
    for (int g = 0; g < 8; ++g) {
        int col = g * 16 + (l & 15);
        float bg = bias[col], alg = attl[col], arg = attr[col];
        int h = g >> 1;
#pragma unroll
        for (int r = 0; r < 4; ++r) {
            float v = acc[g][r] + bg;
            int row = rowbase + r;
            if (row < n) xlb[(size_t)row * DIM + col] = (__bf16)v;
            pl[r][h]  = fmaf(v, alg, pl[r][h]);
            pr2[r][h] = fmaf(v, arg, pr2[r][h]);
        }
    }
#pragma unroll
    for (int off = 1; off <= 8; off <<= 1) {
#pragma unroll
        for (int r = 0; r < 4; ++r)
#pragma unroll
            for (int h = 0; h < 4; ++h) {
                pl[r][h]  += __shfl_xor(pl[r][h], off);
                pr2[r][h] += __shfl_xor(pr2[r][h], off);
            }
    }
    if ((l & 15) == 0) {
#pragma unroll
        for (int r = 0; r < 4; ++r) {
            int row = rowbase + r;
            if (row < n) {
#pragma unroll
                for (int h = 0; h < 4; ++h) {
                    al[row * 4 + h] = pl[r][h];
                    ar[row * 4 + h] = pr2[r][h];
                }
            }
        }
    }
}

template<bool ABF>
__global__ __launch_bounds__(256) void gemm_mfma(
    const float* __restrict__ inF, const unsigned short* __restrict__ inB,
    const uint4* __restrict__ Wb4, const float* __restrict__ bias,
    const float* __restrict__ attl, const float* __restrict__ attr,
    __bf16* __restrict__ xlb, float* __restrict__ al, float* __restrict__ ar, int n)
{
    gemm_body<ABF>(inF, inB, Wb4, bias, attl, attr, xlb, al, ar, n, blockIdx.x);
}

// ---- merged: layer-0 GEMM (blocks < gemmBlocks) + edge scatter (rest) ----
// The two are independent; merging hides the scatter's cross-XCD write
// latency under the GEMM instead of serializing two dispatches.
__global__ __launch_bounds__(256) void gemm0_scatter(
    const float* __restrict__ inF, const uint4* __restrict__ Wb4,
    const float* __restrict__ bias,
    const float* __restrict__ attl, const float* __restrict__ attr,
    __bf16* __restrict__ xlb, float* __restrict__ al, float* __restrict__ ar,
    int n, int gemmBlocks,
    const int* __restrict__ src, const int* __restrict__ dst,
    int* __restrict__ wpos, int* __restrict__ col, int E)
{
    if ((int)blockIdx.x < gemmBlocks) {
        gemm_body<false>(inF, nullptr, Wb4, bias, attl, attr, xlb, al, ar, n, blockIdx.x);
    } else {
        int e = (blockIdx.x - gemmBlocks) * 256 + threadIdx.x;
        if (e < E) {
            int p = atomicAdd(&wpos[dst[e]], 1);
            col[p] = src[e];
        }
    }
}

// ---------------- CSR build ----------------
__global__ __launch_bounds__(256) void deg_count(
    const int* __restrict__ dst, int* __restrict__ deg, int E)
{
    int e = blockIdx.x * blockDim.x + threadIdx.x;
    if (e < E) atomicAdd(&deg[dst[e]], 1);
}

__global__ __launch_bounds__(256) void scan_blocks(
    const int* __restrict__ deg, int* __restrict__ rowptr,
    int* __restrict__ partials, int n)
{
    __shared__ int tot[256];
    int t = threadIdx.x;
    int base = blockIdx.x * 1024 + t * 4;
    int v[4];
#pragma unroll
    for (int j = 0; j < 4; ++j) v[j] = (base + j < n) ? deg[base + j] : 0;
    int p1 = v[0], p2 = p1 + v[1], p3 = p2 + v[2], sum4 = p3 + v[3];
    tot[t] = sum4;
    __syncthreads();
    int val = sum4;
    for (int off = 1; off < 256; off <<= 1) {
        int other = (t >= off) ? tot[t - off] : 0;
        __syncthreads();
        val += other;
        tot[t] = val;
        __syncthreads();
    }
    int excl = val - sum4;
    if (base < n)     rowptr[base]     = excl;
    if (base+1 < n)   rowptr[base+1]   = excl + p1;
    if (base+2 < n)   rowptr[base+2]   = excl + p2;
    if (base+3 < n)   rowptr[base+3]   = excl + p3;
    if (t == 255) partials[blockIdx.x] = val;
}

__global__ __launch_bounds__(256) void scan_partials(
    int* __restrict__ partials, int nb, int* __restrict__ rowptr, int n)
{
    __shared__ int tot[256];
    int t = threadIdx.x;
    int v = (t < nb) ? partials[t] : 0;
    tot[t] = v;
    __syncthreads();
    int val = v;
    for (int off = 1; off < 256; off <<= 1) {
        int other = (t >= off) ? tot[t - off] : 0;
        __syncthreads();
        val += other;
        tot[t] = val;
        __syncthreads();
    }
    if (t < nb) partials[t] = val - v;
    if (t == 255) rowptr[n] = val;
}

__global__ __launch_bounds__(256) void add_offsets(
    int* __restrict__ rowptr, int* __restrict__ wpos,
    const int* __restrict__ partials, int n)
{
    int base = blockIdx.x * 1024 + threadIdx.x * 4;
    int off = partials[blockIdx.x];
#pragma unroll
    for (int j = 0; j < 4; ++j) {
        int i = base + j;
        if (i < n) { int r = rowptr[i] + off; rowptr[i] = r; wpos[i] = r; }
    }
}

// ---- accumulate chunk of <=64 staged edges; 2 edges wide (32 lanes x 4ch) ----
__device__ __forceinline__ void agg_chunk2(
    const int* __restrict__ slds, const float* __restrict__ wl,
    int cn, int q, const unsigned short* __restrict__ xp,
    f32x4& A, f32x4& B, f32x4& C, f32x4& D)
{
    int i = 0;
    for (; i + 8 <= cn; i += 8) {
        int e0 = i + q, e1 = i + 2 + q, e2 = i + 4 + q, e3 = i + 6 + q;
        int s0 = slds[e0], s1 = slds[e1], s2 = slds[e2], s3 = slds[e3];
        float w0 = wl[e0*4], w1 = wl[e1*4], w2 = wl[e2*4], w3 = wl[e3*4];
        ushort4 v0 = *(const ushort4*)(xp + (size_t)s0 * DIM);
        ushort4 v1 = *(const ushort4*)(xp + (size_t)s1 * DIM);
        ushort4 v2 = *(const ushort4*)(xp + (size_t)s2 * DIM);
        ushort4 v3 = *(const ushort4*)(xp + (size_t)s3 * DIM);
        A[0] = fmaf(w0, bf2f(v0.x), A[0]); A[1] = fmaf(w0, bf2f(v0.y), A[1]);
        A[2] = fmaf(w0, bf2f(v0.z), A[2]); A[3] = fmaf(w0, bf2f(v0.w), A[3]);
        B[0] = fmaf(w1, bf2f(v1.x), B[0]); B[1] = fmaf(w1, bf2f(v1.y), B[1]);
        B[2] = fmaf(w1, bf2f(v1.z), B[2]); B[3] = fmaf(w1, bf2f(v1.w), B[3]);
        C[0] = fmaf(w2, bf2f(v2.x), C[0]); C[1] = fmaf(w2, bf2f(v2.y), C[1]);
        C[2] = fmaf(w2, bf2f(v2.z), C[2]); C[3] = fmaf(w2, bf2f(v2.w), C[3]);
        D[0] = fmaf(w3, bf2f(v3.x), D[0]); D[1] = fmaf(w3, bf2f(v3.y), D[1]);
        D[2] = fmaf(w3, bf2f(v3.z), D[2]); D[3] = fmaf(w3, bf2f(v3.w), D[3]);
    }
    for (; i < cn; i += 2) {
        int e = i + q;
        if (e < cn) {
            int s = slds[e];
            float w = wl[e*4];
            ushort4 v = *(const ushort4*)(xp + (size_t)s * DIM);
            A[0] = fmaf(w, bf2f(v.x), A[0]); A[1] = fmaf(w, bf2f(v.y), A[1]);
            A[2] = fmaf(w, bf2f(v.z), A[2]); A[3] = fmaf(w, bf2f(v.w), A[3]);
        }
    }
}

// ---------------- fused per-node softmax + aggregate (bf16 gather) ----------
// one wave per dst node; q=lane>>5 edge parity, c32=lane&31 owns ch 4*c32..+3.
// Output: relu'd bf16 h row (all consumers want relu(h)).
__global__ __launch_bounds__(256) void gat_aggregate(
    const int* __restrict__ rowptr, const int* __restrict__ col,
    const float* __restrict__ al, const float* __restrict__ ar,
    const unsigned short* __restrict__ xlb, unsigned short* __restrict__ outb, int n)
{
    __shared__ float4 wlds[4][64];
    __shared__ int    slds[4][64];
    int wid = threadIdx.x >> 6;
    int node = blockIdx.x * 4 + wid;
    if (node >= n) return;
    int lane = threadIdx.x & 63;
    int q = lane >> 5, c32 = lane & 31;
    int h = c32 >> 3;
    int r0 = rowptr[node], r1 = rowptr[node + 1];
    int deg = r1 - r0;
    unsigned short* po = outb + (size_t)node * DIM + c32 * 4;
    if (deg == 0) {
        if (q == 0) *(ushort4*)po = make_ushort4(0, 0, 0, 0);
        return;
    }

    float4 arv = *(const float4*)(ar + (size_t)node * 4);
    const float* wl = (const float*)&wlds[wid][0] + h;
    const unsigned short* xp = xlb + c32 * 4;
    f32x4 A = {0.f,0.f,0.f,0.f}, B = {0.f,0.f,0.f,0.f};
    f32x4 C = {0.f,0.f,0.f,0.f}, D = {0.f,0.f,0.f,0.f};
    float4 inv4;

    if (deg <= 64) {
        float4 l4 = make_float4(-1e30f, -1e30f, -1e30f, -1e30f);
        int s = 0;
        if (lane < deg) {
            s = col[r0 + lane];
            float4 a = *(const float4*)(al + (size_t)s * 4);
            l4 = lrelu4(arv, a);
        }
        float4 m4 = redmax4(l4);
        float4 p4 = make_float4(0.f, 0.f, 0.f, 0.f);
        if (lane < deg) {
            p4.x = __expf(l4.x - m4.x); p4.y = __expf(l4.y - m4.y);
            p4.z = __expf(l4.z - m4.z); p4.w = __expf(l4.w - m4.w);
        }
        float4 s4 = redsum4(p4);
        inv4 = make_float4(1.f/(s4.x+1e-16f), 1.f/(s4.y+1e-16f),
                           1.f/(s4.z+1e-16f), 1.f/(s4.w+1e-16f));
        if (lane < deg) { wlds[wid][lane] = p4; slds[wid][lane] = s; }
        __asm__ volatile("s_waitcnt lgkmcnt(0)" ::: "memory");
        __builtin_amdgcn_sched_barrier(0);
        agg_chunk2(&slds[wid][0], wl, deg, q, xp, A, B, C, D);
    } else {
        float4 m4 = make_float4(-1e30f, -1e30f, -1e30f, -1e30f);
        for (int i = lane; i < deg; i += 64) {
            int s = col[r0 + i];
            float4 a = *(const float4*)(al + (size_t)s * 4);
            float4 t = lrelu4(arv, a);
            m4.x = fmaxf(m4.x, t.x); m4.y = fmaxf(m4.y, t.y);
            m4.z = fmaxf(m4.z, t.z); m4.w = fmaxf(m4.w, t.w);
        }
        m4 = redmax4(m4);
        float4 s4 = make_float4(0.f, 0.f, 0.f, 0.f);
        for (int i = lane; i < deg; i += 64) {
            int s = col[r0 + i];
            float4 a = *(const float4*)(al + (size_t)s * 4);
            float4 t = lrelu4(arv, a);
            s4.x += __expf(t.x - m4.x); s4.y += __expf(t.y - m4.y);
            s4.z += __expf(t.z - m4.z); s4.w += __expf(t.w - m4.w);
        }
        s4 = redsum4(s4);
        inv4 = make_float4(1.f/(s4.x+1e-16f), 1.f/(s4.y+1e-16f),
                           1.f/(s4.z+1e-16f), 1.f/(s4.w+1e-16f));
        for (int c0 = 0; c0 < deg; c0 += 64) {
            int cn = min(64, deg - c0);
            if (lane < cn) {
                int s = col[r0 + c0 + lane];
                float4 a = *(const float4*)(al + (size_t)s * 4);
                float4 t = lrelu4(arv, a);
                float4 p;
                p.x = __expf(t.x - m4.x); p.y = __expf(t.y - m4.y);
                p.z = __expf(t.z - m4.z); p.w = __expf(t.w - m4.w);
                wlds[wid][lane] = p; slds[wid][lane] = s;
            }
            __asm__ volatile("s_waitcnt lgkmcnt(0)" ::: "memory");
            __builtin_amdgcn_sched_barrier(0);
            agg_chunk2(&slds[wid][0], wl, cn, q, xp, A, B, C, D);
            __asm__ volatile("s_waitcnt lgkmcnt(0)" ::: "memory");
            __builtin_amdgcn_sched_barrier(0);
        }
    }
    float invh = (h == 0) ? inv4.x : (h == 1) ? inv4.y : (h == 2) ? inv4.z : inv4.w;
    f32x4 T;
#pragma unroll
    for (int j = 0; j < 4; ++j) {
        T[j] = A[j] + B[j] + C[j] + D[j];
        T[j] += __shfl_xor(T[j], 32);
    }
    if (q == 0) {
        ushort4 o4;
        o4.x = f2bf(fmaxf(T[0] * invh, 0.f));
        o4.y = f2bf(fmaxf(T[1] * invh, 0.f));
        o4.z = f2bf(fmaxf(T[2] * invh, 0.f));
        o4.w = f2bf(fmaxf(T[3] * invh, 0.f));
        *(ushort4*)po = o4;
    }
}

// ---------------- graph pooling: segmented (batch sorted); h already relu'd bf16 ----
__global__ __launch_bounds__(256) void pool_nodes_seg(
    const unsigned short* __restrict__ h, const int* __restrict__ batch,
    float* __restrict__ pooled, int n)
{
    int wid = threadIdx.x >> 6;
    int lane = threadIdx.x & 63;
    int start = blockIdx.x * POOL_CHUNK;
    int end = min(start + POOL_CHUNK, n);
    float a0 = 0.f, a1 = 0.f;
    int curg = -1;
    for (int node = start + wid; node < end; node += 4) {
        int g = batch[node];
        if (g != curg) {
            if (curg >= 0) {
                unsafeAtomicAdd(pooled + (size_t)curg * DIM + lane*2,     a0);
                unsafeAtomicAdd(pooled + (size_t)curg * DIM + lane*2 + 1, a1);
            }
            curg = g; a0 = 0.f; a1 = 0.f;
        }
        ushort2 v = *(const ushort2*)(h + (size_t)node * DIM + lane * 2);
        a0 += bf2f(v.x);
        a1 += bf2f(v.y);
    }
    if (curg >= 0) {
        unsafeAtomicAdd(pooled + (size_t)curg * DIM + lane*2,     a0);
        unsafeAtomicAdd(pooled + (size_t)curg * DIM + lane*2 + 1, a1);
    }
}

// ---------------- final projection ----------------
__global__ __launch_bounds__(256) void proj_out(
    const float* __restrict__ pooled, const float* __restrict__ W,
    const float* __restrict__ b, float* __restrict__ out, int G)
{
    int idx = blockIdx.x * blockDim.x + threadIdx.x;
    if (idx >= G * 32) return;
    int g = idx >> 5, j = idx & 31;
    const float* pr = pooled + (size_t)g * DIM;
    const float* wr = W + (size_t)j * DIM;
    float acc = 0.f;
#pragma unroll
    for (int k = 0; k < DIM; ++k) acc = fmaf(pr[k], wr[k], acc);
    out[idx] = acc + b[j];
}

extern "C" void kernel_launch(void* const* d_in, const int* in_sizes, int n_in,
                              void* d_out, int out_size, void* d_ws, size_t ws_size,
                              hipStream_t stream)
{
    const float* x      = (const float*)d_in[0];
    const int*   eidx   = (const int*)d_in[1];
    const int*   batch  = (const int*)d_in[2];
    const float* Ws     = (const float*)d_in[3];
    const float* bs     = (const float*)d_in[4];
    const float* attls  = (const float*)d_in[5];
    const float* attrs  = (const float*)d_in[6];
    const float* projW  = (const float*)d_in[7];
    const float* projb  = (const float*)d_in[8];

    const int N = in_sizes[0] / DIM;
    const int E = in_sizes[1] / 2;
    const int G = out_size / 32;
    const int* src = eidx;
    const int* dst = eidx + E;

    char* ws = (char*)d_ws;
    size_t o = 0;
    auto alloc = [&](size_t bytes) { char* p = ws + o; o += (bytes + 255) & ~255ull; return p; };
    unsigned short* hA  = (unsigned short*)alloc((size_t)N * DIM * 2);
    unsigned short* hB  = (unsigned short*)alloc((size_t)N * DIM * 2);
    __bf16* xlb    = (__bf16*)alloc((size_t)N * DIM * 2);
    float*  al     = (float*)alloc((size_t)N * 4 * 4);
    float*  ar     = (float*)alloc((size_t)N * 4 * 4);
    int*    rowptr = (int*)alloc((size_t)(N + 1) * 4);
    int*    wpos   = (int*)alloc((size_t)N * 4);
    int*    deg    = (int*)alloc((size_t)N * 4);
    int*    colv   = (int*)alloc((size_t)E * 4);
    int*    parts  = (int*)alloc(256 * 4);
    float*  pooled = (float*)alloc((size_t)G * DIM * 4);
    __bf16* Wb     = (__bf16*)alloc((size_t)3 * 16384 * 2);

    // ---- one-time prep: W fragment pack + CSR build ----
    const int wtot = 3 * 16384;
    pack_w<<<(wtot + 255) / 256, 256, 0, stream>>>(Ws, Wb, wtot);

    const int nb = (N + 1023) / 1024;
    hipMemsetAsync(deg, 0, (size_t)N * 4, stream);
    deg_count<<<(E + 255) / 256, 256, 0, stream>>>(dst, deg, E);
    scan_blocks<<<nb, 256, 0, stream>>>(deg, rowptr, parts, N);
    scan_partials<<<1, 256, 0, stream>>>(parts, nb, rowptr, N);
    add_offsets<<<nb, 256, 0, stream>>>(rowptr, wpos, parts, N);

    const int gb = (N + 63) / 64;
    const int sb = (E + 255) / 256;

    // ---- layer 0 GEMM merged with edge scatter (independent work) ----
    gemm0_scatter<<<gb + sb, 256, 0, stream>>>(
        x, (const uint4*)Wb, bs, attls, attrs, xlb, al, ar, N, gb,
        src, dst, wpos, colv, E);
    gat_aggregate<<<(N + 3) / 4, 256, 0, stream>>>(rowptr, colv, al, ar,
        (const unsigned short*)xlb, hA, N);

    // ---- layers 1,2 (bf16 A) ----
    const unsigned short* hin = hA;
    unsigned short* houts[2] = {hB, hA};
    for (int l = 1; l < 3; ++l) {
        unsigned short* hout = houts[l - 1];
        const uint4* Wb4 = (const uint4*)(Wb + (size_t)l * 16384);
        gemm_mfma<true><<<gb, 256, 0, stream>>>(nullptr, hin, Wb4, bs + l*DIM,
            attls + l*DIM, attrs + l*DIM, xlb, al, ar, N);
        gat_aggregate<<<(N + 3) / 4, 256, 0, stream>>>(rowptr, colv, al, ar,
            (const unsigned short*)xlb, hout, N);
        hin = hout;
    }

    // ---- pool + projection ----
    hipMemsetAsync(pooled, 0, (size_t)G * DIM * 4, stream);
    pool_nodes_seg<<<(N + POOL_CHUNK - 1) / POOL_CHUNK, 256, 0, stream>>>(hA, batch, pooled, N);
    proj_out<<<(G * 32 + 255) / 256, 256, 0, stream>>>(pooled, projW, projb, (float*)d_out, G);
}